// Round 6
// baseline (137.864 us; speedup 1.0000x reference)
//
#include <hip/hip_runtime.h>

#define SMOOTH 1e-5f

typedef float floatx4 __attribute__((ext_vector_type(4)));
typedef float floatx2 __attribute__((ext_vector_type(2)));

// ws[scale][img][5] = {C, S, inter, z_sum, p_sum}

__device__ __forceinline__ float wave_reduce(float v) {
#pragma unroll
    for (int off = 32; off; off >>= 1) v += __shfl_down(v, off, 64);
    return v;
}

__device__ __forceinline__ float sigmoidf(float x) {
    return 1.f / (1.f + __expf(-x));
}

// Streaming, LDS-free. Per-wave uniform row geometry: each wave owns whole
// rows, so y-edge handling is wave-uniform (SGPR selects, no divergence).
// All loads per thread are independent and issued before any use (MLP).
//   scale0: 4096 blocks, 1 block = 4 full rows (8 px/thread)
//   scale1: 2048 blocks, 1 block = 4 ds rows  (4 px/thread)
//   scale2: 1024 blocks, 1 block = 4 ds rows  (2 px/thread)
__global__ __launch_bounds__(256) void bdou_reduce(
    const float* __restrict__ l0, const float* __restrict__ l1,
    const float* __restrict__ l2, const int* __restrict__ tgt,
    float* __restrict__ ws)
{
    const int blk  = blockIdx.x;
    const int tid  = threadIdx.x;
    const int r    = tid >> 6, lane = tid & 63;

    int scale, img, y0;
    if (blk < 4096)      { scale = 0; img = blk >> 7; y0 = (blk & 127) * 4; }
    else if (blk < 6144) { int b = blk - 4096; scale = 1; img = b >> 6; y0 = (b & 63) * 4; }
    else                 { int b = blk - 6144; scale = 2; img = b >> 5; y0 = (b & 31) * 4; }

    const int* __restrict__ timg = tgt + (size_t)img * 262144;

    int   cC = 0, cS = 0;
    float aI = 0.f, aZ = 0.f, aP = 0.f;

    if (scale == 0) {
        const int y = y0 + r;                 // 0..511, wave-uniform
        const int c = lane * 8;               // 0..504
        const float* Lp = l0 + (size_t)img * 262144 + (size_t)y * 512 + c;
        const int*  Crow = timg + (size_t)y * 512 + c;
        const int ou = (y > 0)   ? -512 : 0;
        const int od = (y < 511) ?  512 : 0;
        const int mu = (y > 0)   ? -1 : 0;    // wave-uniform masks
        const int md = (y < 511) ? -1 : 0;
        // ---- issue all 10 loads ----
        floatx4 la = *reinterpret_cast<const floatx4*>(Lp);
        floatx4 lb = *reinterpret_cast<const floatx4*>(Lp + 4);
        int4 tc0 = *reinterpret_cast<const int4*>(Crow);
        int4 tc1 = *reinterpret_cast<const int4*>(Crow + 4);
        int4 tu0 = *reinterpret_cast<const int4*>(Crow + ou);
        int4 tu1 = *reinterpret_cast<const int4*>(Crow + ou + 4);
        int4 td0 = *reinterpret_cast<const int4*>(Crow + od);
        int4 td1 = *reinterpret_cast<const int4*>(Crow + od + 4);
        int lfv = Crow[(c > 0)   ? -1 : 0];
        int rtv = Crow[(c < 504) ?  8 : 0];
        // ---- compute ----
        int t[8] = {tc0.x, tc0.y, tc0.z, tc0.w, tc1.x, tc1.y, tc1.z, tc1.w};
        int u[8] = {tu0.x & mu, tu0.y & mu, tu0.z & mu, tu0.w & mu,
                    tu1.x & mu, tu1.y & mu, tu1.z & mu, tu1.w & mu};
        int d[8] = {td0.x & md, td0.y & md, td0.z & md, td0.w & md,
                    td1.x & md, td1.y & md, td1.z & md, td1.w & md};
        float pr[8] = {sigmoidf(la.x), sigmoidf(la.y), sigmoidf(la.z), sigmoidf(la.w),
                       sigmoidf(lb.x), sigmoidf(lb.y), sigmoidf(lb.z), sigmoidf(lb.w)};
        int lf = (c > 0) ? lfv : 0;
        int rt = (c < 504) ? rtv : 0;
#pragma unroll
        for (int j = 0; j < 8; ++j) {
            int lv = (j == 0) ? lf : t[j - 1];
            int rv = (j == 7) ? rt : t[j + 1];
            int tb = t[j] != 0;
            cS += tb;
            cC += tb & ~((u[j] != 0) & (d[j] != 0) & (lv != 0) & (rv != 0));
            aI += pr[j] * (float)tb;
            aZ += pr[j] * pr[j];
            aP += pr[j];
        }
    } else if (scale == 1) {
        const int y  = y0 + r;                // ds row 0..255
        const int c0 = lane * 4;              // ds col 0..252
        const float* Lp = l1 + (size_t)img * 65536 + (size_t)y * 256 + c0;
        const int*  Crow = timg + (size_t)(y * 2) * 512 + c0 * 2;
        const int ou = (y > 0)   ? -1024 : 0;
        const int od = (y < 255) ?  1024 : 0;
        const int mu = (y > 0)   ? -1 : 0;
        const int md = (y < 255) ? -1 : 0;
        floatx4 lg = *reinterpret_cast<const floatx4*>(Lp);
        int4 cc0 = *reinterpret_cast<const int4*>(Crow);
        int4 cc1 = *reinterpret_cast<const int4*>(Crow + 4);
        int4 uu0 = *reinterpret_cast<const int4*>(Crow + ou);
        int4 uu1 = *reinterpret_cast<const int4*>(Crow + ou + 4);
        int4 dd0 = *reinterpret_cast<const int4*>(Crow + od);
        int4 dd1 = *reinterpret_cast<const int4*>(Crow + od + 4);
        int lfv = Crow[(c0 > 0)   ? -2 : 0];
        int rtv = Crow[(c0 < 252) ?  8 : 0];
        int t[4] = {cc0.x, cc0.z, cc1.x, cc1.z};
        int u[4] = {uu0.x & mu, uu0.z & mu, uu1.x & mu, uu1.z & mu};
        int d[4] = {dd0.x & md, dd0.z & md, dd1.x & md, dd1.z & md};
        float pr[4] = {sigmoidf(lg.x), sigmoidf(lg.y), sigmoidf(lg.z), sigmoidf(lg.w)};
        int lf = (c0 > 0) ? lfv : 0;
        int rt = (c0 < 252) ? rtv : 0;
#pragma unroll
        for (int j = 0; j < 4; ++j) {
            int lv = (j == 0) ? lf : t[j - 1];
            int rv = (j == 3) ? rt : t[j + 1];
            int tb = t[j] != 0;
            cS += tb;
            cC += tb & ~((u[j] != 0) & (d[j] != 0) & (lv != 0) & (rv != 0));
            aI += pr[j] * (float)tb;
            aZ += pr[j] * pr[j];
            aP += pr[j];
        }
    } else {
        const int y  = y0 + r;                // ds row 0..127
        const int c0 = lane * 2;              // ds col 0..126
        const float* Lp = l2 + (size_t)img * 16384 + (size_t)y * 128 + c0;
        const int*  Crow = timg + (size_t)(y * 4) * 512 + c0 * 4;
        const int ou = (y > 0)   ? -2048 : 0;
        const int od = (y < 127) ?  2048 : 0;
        const int mu = (y > 0)   ? -1 : 0;
        const int md = (y < 127) ? -1 : 0;
        floatx2 lg = *reinterpret_cast<const floatx2*>(Lp);
        int t0v = Crow[0], t1v = Crow[4];
        int u0v = Crow[ou], u1v = Crow[ou + 4];
        int d0v = Crow[od], d1v = Crow[od + 4];
        int lfv = Crow[(c0 > 0)   ? -4 : 0];
        int rtv = Crow[(c0 < 126) ?  8 : 0];
        int t[2] = {t0v, t1v};
        int u[2] = {u0v & mu, u1v & mu};
        int d[2] = {d0v & md, d1v & md};
        float pr[2] = {sigmoidf(lg.x), sigmoidf(lg.y)};
        int lf = (c0 > 0) ? lfv : 0;
        int rt = (c0 < 126) ? rtv : 0;
#pragma unroll
        for (int j = 0; j < 2; ++j) {
            int lv = (j == 0) ? lf : t[0];
            int rv = (j == 1) ? rt : t[1];
            int tb = t[j] != 0;
            cS += tb;
            cC += tb & ~((u[j] != 0) & (d[j] != 0) & (lv != 0) & (rv != 0));
            aI += pr[j] * (float)tb;
            aZ += pr[j] * pr[j];
            aP += pr[j];
        }
    }

    // ---- block reduce 5 partials, atomic into ws ----
    float vals[5] = {(float)cC, (float)cS, aI, aZ, aP};
    __shared__ float red[4][5];
#pragma unroll
    for (int k = 0; k < 5; ++k) vals[k] = wave_reduce(vals[k]);
    if (lane == 0) {
#pragma unroll
        for (int k = 0; k < 5; ++k) red[r][k] = vals[k];
    }
    __syncthreads();
    if (tid < 5) {
        float s = red[0][tid] + red[1][tid] + red[2][tid] + red[3][tid];
        atomicAdd(&ws[(scale * 32 + img) * 5 + tid], s);
    }
}

// 128 threads: tid<96 -> one (scale,img) pair each; wave+LDS reduce.
__global__ void bdou_final(const float* __restrict__ ws,
                           const float* __restrict__ valid_mask,
                           float* __restrict__ out)
{
    int tid = threadIdx.x;
    float contrib = 0.f, cpart = 0.f;
    if (tid < 96) {
        int s = tid >> 5, i = tid & 31;
        const float* w = ws + tid * 5;
        float C = w[0], S = w[1], I = w[2], Z = w[3], P = w[4];
        float valid = (valid_mask[i] >= 0.5f) ? 1.f : 0.f;
        float alpha = fminf(2.f * (1.f - (C + SMOOTH) / (S + SMOOTH)) - 1.f, 0.8f);
        float dou = (Z + S - 2.f * I + SMOOTH) /
                    (Z + S - (1.f + alpha) * I + SMOOTH);
        const float wts[3]  = {4.f / 7.f, 2.f / 7.f, 1.f / 7.f};
        const float pixc[3] = {262144.f, 65536.f, 16384.f};
        float per = (S > 0.f) ? dou : (P / pixc[s]);
        contrib = wts[s] * per * valid;
        if (tid < 32) cpart = valid;
    }
    contrib = wave_reduce(contrib);
    cpart   = wave_reduce(cpart);
    __shared__ float sm[2][2];
    int wv = tid >> 6, ln = tid & 63;
    if (ln == 0) { sm[wv][0] = contrib; sm[wv][1] = cpart; }
    __syncthreads();
    if (tid == 0) {
        float tot = sm[0][0] + sm[1][0];
        float cnt = sm[0][1] + sm[1][1];
        out[0] = (cnt > 0.f) ? tot / cnt : 0.f;
    }
}

extern "C" void kernel_launch(void* const* d_in, const int* in_sizes, int n_in,
                              void* d_out, int out_size, void* d_ws, size_t ws_size,
                              hipStream_t stream) {
    const float* l0 = (const float*)d_in[0];
    const float* l1 = (const float*)d_in[1];
    const float* l2 = (const float*)d_in[2];
    const int*   tg = (const int*)d_in[3];
    const float* vm = (const float*)d_in[4];
    float* ws = (float*)d_ws;

    (void)hipMemsetAsync(ws, 0, 3 * 32 * 5 * sizeof(float), stream);
    bdou_reduce<<<7168, 256, 0, stream>>>(l0, l1, l2, tg, ws);
    bdou_final<<<1, 128, 0, stream>>>(ws, vm, (float*)d_out);
}

// Round 7
// 113.066 us; speedup vs baseline: 1.2193x; 1.2193x over previous
//
#include <hip/hip_runtime.h>

#define SMOOTH 1e-5f

typedef float floatx4 __attribute__((ext_vector_type(4)));
typedef float floatx2 __attribute__((ext_vector_type(2)));

// ws[scale][img][5] = {C, S, inter, z_sum, p_sum}

__device__ __forceinline__ float wave_reduce(float v) {
#pragma unroll
    for (int off = 32; off; off >>= 1) v += __shfl_down(v, off, 64);
    return v;
}

__device__ __forceinline__ float sigmoidf(float x) {
    return 1.f / (1.f + __expf(-x));
}

__device__ __forceinline__ unsigned pack8(int4 a, int4 b) {
    return (unsigned)(a.x != 0)        | ((unsigned)(a.y != 0) << 1) |
           ((unsigned)(a.z != 0) << 2) | ((unsigned)(a.w != 0) << 3) |
           ((unsigned)(b.x != 0) << 4) | ((unsigned)(b.y != 0) << 5) |
           ((unsigned)(b.z != 0) << 6) | ((unsigned)(b.w != 0) << 7);
}
__device__ __forceinline__ unsigned pack4(int4 a, int4 b) {   // even elements
    return (unsigned)(a.x != 0)        | ((unsigned)(a.z != 0) << 1) |
           ((unsigned)(b.x != 0) << 2) | ((unsigned)(b.z != 0) << 3);
}
__device__ __forceinline__ unsigned pack2(int a, int b) {
    return (unsigned)(a != 0) | ((unsigned)(b != 0) << 1);
}

// Bit-stencil one row of W px/lane. u,c,d = packed fg bits; pr = probs.
template<int W>
__device__ __forceinline__ void row_proc(unsigned u, unsigned c, unsigned d,
    const float* pr, int lane, int& cC, int& cS, float& aI, float& aZ, float& aP)
{
    unsigned pv = __shfl_up(c, 1);
    unsigned nx = __shfl_down(c, 1);
    if (lane == 0)  pv = 0;
    if (lane == 63) nx = 0;
    const unsigned M = (1u << W) - 1u;
    unsigned lv = ((c << 1) | ((pv >> (W - 1)) & 1u)) & M;
    unsigned rv = ((c >> 1) | ((nx & 1u) << (W - 1))) & M;
    unsigned inter = c & u & d & lv & rv;
    cS += __popc(c);
    cC += __popc(c & ~inter);
#pragma unroll
    for (int j = 0; j < W; ++j) {
        float pj = pr[j];
        aI += ((c >> j) & 1u) ? pj : 0.f;
        aZ += pj * pj;
        aP += pj;
    }
}

// 1792 blocks, 256 thr. Wave = one full row width; each wave slides down 4 rows.
//   scale0: blk 0..1023    (32/img): block = 16 full rows,  8 px/lane/row
//   scale1: blk 1024..1535 (16/img): block = 16 ds rows,    4 px/lane/row
//   scale2: blk 1536..1791 ( 8/img): block = 16 ds rows,    2 px/lane/row
// Targets loaded once per row (6 rows per 4 computed), packed to bits.
__global__ __launch_bounds__(256) void bdou_reduce(
    const float* __restrict__ l0, const float* __restrict__ l1,
    const float* __restrict__ l2, const int* __restrict__ tgt,
    float* __restrict__ ws)
{
    const int blk = blockIdx.x;
    const int tid = threadIdx.x;
    const int w   = tid >> 6, lane = tid & 63;

    int scale, img, rb;
    if (blk < 1024)      { scale = 0; img = blk >> 5; rb = blk & 31; }
    else if (blk < 1536) { int b = blk - 1024; scale = 1; img = b >> 4; rb = b & 15; }
    else                 { int b = blk - 1536; scale = 2; img = b >> 3; rb = b & 7; }

    const int* __restrict__ timg = tgt + (size_t)img * 262144;
    const int y0 = rb * 16 + w * 4;          // wave-uniform first row

    int   cC = 0, cS = 0;
    float aI = 0.f, aZ = 0.f, aP = 0.f;

    if (scale == 0) {
        const int cc = lane * 8;
        const int* T = timg + (size_t)y0 * 512 + cc;
        const float* L = l0 + (size_t)img * 262144 + (size_t)y0 * 512 + cc;
        const int ou = (y0 > 0) ? -512 : 0;
        const unsigned mu = (y0 > 0) ? 0xFFu : 0u;
        const int od = (y0 + 4 <= 511) ? 4 * 512 : 3 * 512;
        const unsigned m4 = (y0 + 4 <= 511) ? 0xFFu : 0u;
        // issue all 20 loads up front
        int4 ru0 = *(const int4*)(T + ou),       ru1 = *(const int4*)(T + ou + 4);
        int4 r00 = *(const int4*)(T),            r01 = *(const int4*)(T + 4);
        int4 r10 = *(const int4*)(T + 512),      r11 = *(const int4*)(T + 512 + 4);
        int4 r20 = *(const int4*)(T + 1024),     r21 = *(const int4*)(T + 1024 + 4);
        int4 r30 = *(const int4*)(T + 1536),     r31 = *(const int4*)(T + 1536 + 4);
        int4 r40 = *(const int4*)(T + od),       r41 = *(const int4*)(T + od + 4);
        floatx4 la0 = *(const floatx4*)(L),              la1 = *(const floatx4*)(L + 4);
        floatx4 lb0 = *(const floatx4*)(L + 512),        lb1 = *(const floatx4*)(L + 512 + 4);
        floatx4 lc0 = *(const floatx4*)(L + 1024),       lc1 = *(const floatx4*)(L + 1024 + 4);
        floatx4 ld0 = *(const floatx4*)(L + 1536),       ld1 = *(const floatx4*)(L + 1536 + 4);
        unsigned bu = pack8(ru0, ru1) & mu;
        unsigned b0 = pack8(r00, r01);
        unsigned b1 = pack8(r10, r11);
        unsigned b2 = pack8(r20, r21);
        unsigned b3 = pack8(r30, r31);
        unsigned b4 = pack8(r40, r41) & m4;
        float pr[8];
        pr[0]=sigmoidf(la0.x); pr[1]=sigmoidf(la0.y); pr[2]=sigmoidf(la0.z); pr[3]=sigmoidf(la0.w);
        pr[4]=sigmoidf(la1.x); pr[5]=sigmoidf(la1.y); pr[6]=sigmoidf(la1.z); pr[7]=sigmoidf(la1.w);
        row_proc<8>(bu, b0, b1, pr, lane, cC, cS, aI, aZ, aP);
        pr[0]=sigmoidf(lb0.x); pr[1]=sigmoidf(lb0.y); pr[2]=sigmoidf(lb0.z); pr[3]=sigmoidf(lb0.w);
        pr[4]=sigmoidf(lb1.x); pr[5]=sigmoidf(lb1.y); pr[6]=sigmoidf(lb1.z); pr[7]=sigmoidf(lb1.w);
        row_proc<8>(b0, b1, b2, pr, lane, cC, cS, aI, aZ, aP);
        pr[0]=sigmoidf(lc0.x); pr[1]=sigmoidf(lc0.y); pr[2]=sigmoidf(lc0.z); pr[3]=sigmoidf(lc0.w);
        pr[4]=sigmoidf(lc1.x); pr[5]=sigmoidf(lc1.y); pr[6]=sigmoidf(lc1.z); pr[7]=sigmoidf(lc1.w);
        row_proc<8>(b1, b2, b3, pr, lane, cC, cS, aI, aZ, aP);
        pr[0]=sigmoidf(ld0.x); pr[1]=sigmoidf(ld0.y); pr[2]=sigmoidf(ld0.z); pr[3]=sigmoidf(ld0.w);
        pr[4]=sigmoidf(ld1.x); pr[5]=sigmoidf(ld1.y); pr[6]=sigmoidf(ld1.z); pr[7]=sigmoidf(ld1.w);
        row_proc<8>(b2, b3, b4, pr, lane, cC, cS, aI, aZ, aP);
    } else if (scale == 1) {
        const int fc = lane * 8;                     // full-res col
        const int* T = timg + (size_t)(2 * y0) * 512 + fc;
        const float* L = l1 + (size_t)img * 65536 + (size_t)y0 * 256 + lane * 4;
        const int ou = (y0 > 0) ? -1024 : 0;
        const unsigned mu = (y0 > 0) ? 0xFu : 0u;
        const int od = (y0 + 4 <= 255) ? 4096 : 3072;
        const unsigned m4 = (y0 + 4 <= 255) ? 0xFu : 0u;
        int4 ru0 = *(const int4*)(T + ou),   ru1 = *(const int4*)(T + ou + 4);
        int4 r00 = *(const int4*)(T),        r01 = *(const int4*)(T + 4);
        int4 r10 = *(const int4*)(T + 1024), r11 = *(const int4*)(T + 1024 + 4);
        int4 r20 = *(const int4*)(T + 2048), r21 = *(const int4*)(T + 2048 + 4);
        int4 r30 = *(const int4*)(T + 3072), r31 = *(const int4*)(T + 3072 + 4);
        int4 r40 = *(const int4*)(T + od),   r41 = *(const int4*)(T + od + 4);
        floatx4 la = *(const floatx4*)(L);
        floatx4 lb = *(const floatx4*)(L + 256);
        floatx4 lc = *(const floatx4*)(L + 512);
        floatx4 ld = *(const floatx4*)(L + 768);
        unsigned bu = pack4(ru0, ru1) & mu;
        unsigned b0 = pack4(r00, r01);
        unsigned b1 = pack4(r10, r11);
        unsigned b2 = pack4(r20, r21);
        unsigned b3 = pack4(r30, r31);
        unsigned b4 = pack4(r40, r41) & m4;
        float pr[4];
        pr[0]=sigmoidf(la.x); pr[1]=sigmoidf(la.y); pr[2]=sigmoidf(la.z); pr[3]=sigmoidf(la.w);
        row_proc<4>(bu, b0, b1, pr, lane, cC, cS, aI, aZ, aP);
        pr[0]=sigmoidf(lb.x); pr[1]=sigmoidf(lb.y); pr[2]=sigmoidf(lb.z); pr[3]=sigmoidf(lb.w);
        row_proc<4>(b0, b1, b2, pr, lane, cC, cS, aI, aZ, aP);
        pr[0]=sigmoidf(lc.x); pr[1]=sigmoidf(lc.y); pr[2]=sigmoidf(lc.z); pr[3]=sigmoidf(lc.w);
        row_proc<4>(b1, b2, b3, pr, lane, cC, cS, aI, aZ, aP);
        pr[0]=sigmoidf(ld.x); pr[1]=sigmoidf(ld.y); pr[2]=sigmoidf(ld.z); pr[3]=sigmoidf(ld.w);
        row_proc<4>(b2, b3, b4, pr, lane, cC, cS, aI, aZ, aP);
    } else {
        const int fc = lane * 8;                     // full-res col
        const int* T = timg + (size_t)(4 * y0) * 512 + fc;
        const float* L = l2 + (size_t)img * 16384 + (size_t)y0 * 128 + lane * 2;
        const int ou = (y0 > 0) ? -2048 : 0;
        const unsigned mu = (y0 > 0) ? 3u : 0u;
        const int od = (y0 + 4 <= 127) ? 8192 : 6144;
        const unsigned m4 = (y0 + 4 <= 127) ? 3u : 0u;
        int ru0 = T[ou],   ru1 = T[ou + 4];
        int r00 = T[0],    r01 = T[4];
        int r10 = T[2048], r11 = T[2048 + 4];
        int r20 = T[4096], r21 = T[4096 + 4];
        int r30 = T[6144], r31 = T[6144 + 4];
        int r40 = T[od],   r41 = T[od + 4];
        floatx2 la = *(const floatx2*)(L);
        floatx2 lb = *(const floatx2*)(L + 128);
        floatx2 lc = *(const floatx2*)(L + 256);
        floatx2 ld = *(const floatx2*)(L + 384);
        unsigned bu = pack2(ru0, ru1) & mu;
        unsigned b0 = pack2(r00, r01);
        unsigned b1 = pack2(r10, r11);
        unsigned b2 = pack2(r20, r21);
        unsigned b3 = pack2(r30, r31);
        unsigned b4 = pack2(r40, r41) & m4;
        float pr[2];
        pr[0]=sigmoidf(la.x); pr[1]=sigmoidf(la.y);
        row_proc<2>(bu, b0, b1, pr, lane, cC, cS, aI, aZ, aP);
        pr[0]=sigmoidf(lb.x); pr[1]=sigmoidf(lb.y);
        row_proc<2>(b0, b1, b2, pr, lane, cC, cS, aI, aZ, aP);
        pr[0]=sigmoidf(lc.x); pr[1]=sigmoidf(lc.y);
        row_proc<2>(b1, b2, b3, pr, lane, cC, cS, aI, aZ, aP);
        pr[0]=sigmoidf(ld.x); pr[1]=sigmoidf(ld.y);
        row_proc<2>(b2, b3, b4, pr, lane, cC, cS, aI, aZ, aP);
    }

    // ---- block reduce 5 partials, atomic into ws ----
    float vals[5] = {(float)cC, (float)cS, aI, aZ, aP};
    __shared__ float red[4][5];
#pragma unroll
    for (int k = 0; k < 5; ++k) vals[k] = wave_reduce(vals[k]);
    if (lane == 0) {
#pragma unroll
        for (int k = 0; k < 5; ++k) red[w][k] = vals[k];
    }
    __syncthreads();
    if (tid < 5) {
        float s = red[0][tid] + red[1][tid] + red[2][tid] + red[3][tid];
        atomicAdd(&ws[(scale * 32 + img) * 5 + tid], s);
    }
}

// 128 threads: tid<96 -> one (scale,img) pair each; wave+LDS reduce.
__global__ void bdou_final(const float* __restrict__ ws,
                           const float* __restrict__ valid_mask,
                           float* __restrict__ out)
{
    int tid = threadIdx.x;
    float contrib = 0.f, cpart = 0.f;
    if (tid < 96) {
        int s = tid >> 5, i = tid & 31;
        const float* w = ws + tid * 5;
        float C = w[0], S = w[1], I = w[2], Z = w[3], P = w[4];
        float valid = (valid_mask[i] >= 0.5f) ? 1.f : 0.f;
        float alpha = fminf(2.f * (1.f - (C + SMOOTH) / (S + SMOOTH)) - 1.f, 0.8f);
        float dou = (Z + S - 2.f * I + SMOOTH) /
                    (Z + S - (1.f + alpha) * I + SMOOTH);
        const float wts[3]  = {4.f / 7.f, 2.f / 7.f, 1.f / 7.f};
        const float pixc[3] = {262144.f, 65536.f, 16384.f};
        float per = (S > 0.f) ? dou : (P / pixc[s]);
        contrib = wts[s] * per * valid;
        if (tid < 32) cpart = valid;
    }
    contrib = wave_reduce(contrib);
    cpart   = wave_reduce(cpart);
    __shared__ float sm[2][2];
    int wv = tid >> 6, ln = tid & 63;
    if (ln == 0) { sm[wv][0] = contrib; sm[wv][1] = cpart; }
    __syncthreads();
    if (tid == 0) {
        float tot = sm[0][0] + sm[1][0];
        float cnt = sm[0][1] + sm[1][1];
        out[0] = (cnt > 0.f) ? tot / cnt : 0.f;
    }
}

extern "C" void kernel_launch(void* const* d_in, const int* in_sizes, int n_in,
                              void* d_out, int out_size, void* d_ws, size_t ws_size,
                              hipStream_t stream) {
    const float* l0 = (const float*)d_in[0];
    const float* l1 = (const float*)d_in[1];
    const float* l2 = (const float*)d_in[2];
    const int*   tg = (const int*)d_in[3];
    const float* vm = (const float*)d_in[4];
    float* ws = (float*)d_ws;

    (void)hipMemsetAsync(ws, 0, 3 * 32 * 5 * sizeof(float), stream);
    bdou_reduce<<<1792, 256, 0, stream>>>(l0, l1, l2, tg, ws);
    bdou_final<<<1, 128, 0, stream>>>(ws, vm, (float*)d_out);
}